// Round 3
// baseline (240.320 us; speedup 1.0000x reference)
//
#include <hip/hip_runtime.h>
#include <hip/hip_bf16.h>
#include <math.h>

#define LOG2PI_F 1.8378770664093453f

typedef __bf16 bf16_t;
typedef bf16_t bf16x8 __attribute__((ext_vector_type(8)));
typedef bf16_t bf16x4 __attribute__((ext_vector_type(4)));
typedef float f32x4 __attribute__((ext_vector_type(4)));

#define M_DIM 16384
#define K_DIM 2048
#define N_DIM 2048
#define BM 256
#define BN 256
#define BK 64
#define NB_N (N_DIM / BN) /* 8 */
#define NB_M (M_DIM / BM) /* 64 */

// async global->LDS, 16B per lane. LDS dest is wave-uniform base + lane*16.
__device__ __forceinline__ void gload16(const void* g, void* l) {
    __builtin_amdgcn_global_load_lds(
        (__attribute__((address_space(1))) void*)g,
        (__attribute__((address_space(3))) void*)l, 16, 0, 0);
}

// ---------------------------------------------------------------------------
// Build Lt[j][i] = L[i][j] in bf16 + partial sums of strict-lower Woff^2.
// ---------------------------------------------------------------------------
__global__ __launch_bounds__(256) void build_Lt(const float* __restrict__ Woff,
                                                const float* __restrict__ Wld,
                                                bf16_t* __restrict__ Lt,
                                                float* __restrict__ misc_arr) {
    __shared__ float tile[64][65];
    __shared__ float red[4];
    const int jt = blockIdx.x * 64;
    const int it = blockIdx.y * 64;
    const int tid = threadIdx.x;
    float ss = 0.f;

    if (it + 63 >= jt) {
        for (int e = tid; e < 4096; e += 256) {
            int r = e >> 6, c = e & 63;
            tile[r][c] = Woff[(size_t)(it + r) * K_DIM + (jt + c)];
        }
    }
    __syncthreads();

    for (int e = tid; e < 4096; e += 256) {
        int jr = e >> 6, ic = e & 63;
        int i = it + ic, j = jt + jr;
        float v = 0.f;
        if (i > j) {
            v = tile[ic][jr];
            ss += v * v;
        } else if (i == j) {
            v = expf(Wld[i]);
        }
        Lt[(size_t)j * K_DIM + i] = (bf16_t)v;
    }

    #pragma unroll
    for (int off = 32; off; off >>= 1) ss += __shfl_down(ss, off);
    if ((tid & 63) == 0) red[tid >> 6] = ss;
    __syncthreads();
    if (tid == 0)
        misc_arr[blockIdx.y * 32 + blockIdx.x] = red[0] + red[1] + red[2] + red[3];
}

// ---------------------------------------------------------------------------
// Cast x -> bf16 and fuse pred_mean GEMV u[b] = dot(x[b], W_mean).
// ---------------------------------------------------------------------------
__global__ __launch_bounds__(256) void prep_x(const float* __restrict__ X,
                                              const float* __restrict__ Wm,
                                              bf16_t* __restrict__ Xb,
                                              float* __restrict__ U) {
    const int b = blockIdx.x;
    const int tid = threadIdx.x;
    const float* xr = X + (size_t)b * K_DIM;
    bf16_t* xo = Xb + (size_t)b * K_DIM;
    __shared__ float red[4];
    float dot = 0.f;
    #pragma unroll
    for (int h = 0; h < 2; ++h) {
        int base = h * 1024 + tid * 4;
        float4 v = *(const float4*)(xr + base);
        float4 w = *(const float4*)(Wm + base);
        dot += v.x * w.x + v.y * w.y + v.z * w.z + v.w * w.w;
        bf16x4 p = {(bf16_t)v.x, (bf16_t)v.y, (bf16_t)v.z, (bf16_t)v.w};
        *(bf16x4*)(xo + base) = p;
    }
    #pragma unroll
    for (int off = 32; off; off >>= 1) dot += __shfl_down(dot, off);
    if ((tid & 63) == 0) red[tid >> 6] = dot;
    __syncthreads();
    if (tid == 0) U[b] = red[0] + red[1] + red[2] + red[3];
}

// ---------------------------------------------------------------------------
// quad_gemm 256x256, BK=64, 8 waves (2M x 4N), dbuf LDS + counted vmcnt.
// Per wave: 128x64 output = acc[8][4] f32x4. 64 MFMA / K-tile / wave.
// Pipeline invariant at loop top: buf[i&1] holds tile i (landed+barriered),
// buf[(i+1)&1] holds tile i+1 (8 loads/wave in flight).
// ---------------------------------------------------------------------------
__device__ __forceinline__ bf16x8 ldsfrag(const bf16_t* base, int row, int ks, int g) {
    int byteoff = ((row * BK + ks * 32 + g * 8) * 2) ^ ((row & 7) << 4);
    return *(const bf16x8*)((const char*)base + byteoff);
}

__global__ __launch_bounds__(512, 2) void quad_gemm(const bf16_t* __restrict__ Xb,
                                                    const bf16_t* __restrict__ Lt,
                                                    float* __restrict__ qpart) {
    __shared__ bf16_t As[2][BM * BK];   // 2 x 32 KB
    __shared__ bf16_t Bs[2][BN * BK];   // 2 x 32 KB   (total 128 KB)

    const int mb = blockIdx.x;
    const int y = blockIdx.y;
    const int nb = (y < 4) ? y : 11 - y;   // pair heavy+light per CU round
    const int tid = threadIdx.x;
    const int lane = tid & 63;
    const int wid = tid >> 6;              // 0..7
    const int wr = wid >> 2, wc = wid & 3; // 2 x 4 wave grid
    const int g = lane >> 4, r16 = lane & 15;
    const int brow = mb * BM, bcol = nb * BN;
    const int NT = (K_DIM - bcol) >> 6;    // 32 - 4*nb, even, >= 4

    // staging source pointers (per-lane, source-swizzled chunk).
    // call (wid,j): LDS rows (wid*4+j)*8 + (lane>>3), chunk lane&7.
    const int srow = lane >> 3;
    const int scol = (lane & 7) ^ srow;
    const bf16_t* pA[4];
    const bf16_t* pB[4];
    #pragma unroll
    for (int j = 0; j < 4; ++j) {
        int row = (wid * 4 + j) * 8 + srow;
        pA[j] = Xb + (size_t)(brow + row) * K_DIM + bcol + scol * 8;
        pB[j] = Lt + (size_t)(bcol + row) * K_DIM + bcol + scol * 8;
    }

#define STAGE(BUF)                                                         \
    { _Pragma("unroll") for (int j = 0; j < 4; ++j) {                      \
          gload16(pA[j], (char*)As[BUF] + (wid * 4 + j) * 1024);           \
          gload16(pB[j], (char*)Bs[BUF] + (wid * 4 + j) * 1024);           \
          pA[j] += BK; pB[j] += BK; } }

    f32x4 acc[8][4];
    const f32x4 zero = {0.f, 0.f, 0.f, 0.f};
    #pragma unroll
    for (int m = 0; m < 8; ++m)
        #pragma unroll
        for (int n = 0; n < 4; ++n) acc[m][n] = zero;

    // prologue: tiles 0,1 -> bufs 0,1; wait tile0 (leave tile1 in flight)
    STAGE(0)
    STAGE(1)
    asm volatile("s_waitcnt vmcnt(8)" ::: "memory");
    asm volatile("s_barrier" ::: "memory");

#define TILE_BODY(BUF, I)                                                          \
    {                                                                              \
        bf16x8 a0[8], b0[4];                                                       \
        _Pragma("unroll") for (int m = 0; m < 8; ++m)                              \
            a0[m] = ldsfrag(As[BUF], wr * 128 + m * 16 + r16, 0, g);               \
        _Pragma("unroll") for (int n = 0; n < 4; ++n)                              \
            b0[n] = ldsfrag(Bs[BUF], wc * 64 + n * 16 + r16, 0, g);                \
        __builtin_amdgcn_s_setprio(1);                                             \
        _Pragma("unroll") for (int m = 0; m < 8; ++m)                              \
            _Pragma("unroll") for (int n = 0; n < 4; ++n)                          \
                acc[m][n] = __builtin_amdgcn_mfma_f32_16x16x32_bf16(               \
                    a0[m], b0[n], acc[m][n], 0, 0, 0);                             \
        __builtin_amdgcn_s_setprio(0);                                             \
        bf16x8 a1[8], b1[4];                                                       \
        _Pragma("unroll") for (int m = 0; m < 8; ++m)                              \
            a1[m] = ldsfrag(As[BUF], wr * 128 + m * 16 + r16, 1, g);               \
        _Pragma("unroll") for (int n = 0; n < 4; ++n)                              \
            b1[n] = ldsfrag(Bs[BUF], wc * 64 + n * 16 + r16, 1, g);                \
        asm volatile("s_waitcnt lgkmcnt(0)" ::: "memory");                         \
        __builtin_amdgcn_sched_barrier(0);                                         \
        asm volatile("s_barrier" ::: "memory"); /* all reads of buf done */        \
        if ((I) + 2 < NT) STAGE(BUF)            /* tile I+2 -> vacated buf */      \
        __builtin_amdgcn_s_setprio(1);                                             \
        _Pragma("unroll") for (int m = 0; m < 8; ++m)                              \
            _Pragma("unroll") for (int n = 0; n < 4; ++n)                          \
                acc[m][n] = __builtin_amdgcn_mfma_f32_16x16x32_bf16(               \
                    a1[m], b1[n], acc[m][n], 0, 0, 0);                             \
        __builtin_amdgcn_s_setprio(0);                                             \
        if ((I) + 2 < NT)                                                          \
            asm volatile("s_waitcnt vmcnt(8)" ::: "memory"); /* tile I+1 landed */ \
        else                                                                       \
            asm volatile("s_waitcnt vmcnt(0)" ::: "memory");                       \
        asm volatile("s_barrier" ::: "memory");                                    \
    }

    for (int i = 0; i < NT; i += 2) {
        TILE_BODY(0, i)
        TILE_BODY(1, i + 1)
    }

    // epilogue: per-row sum of squares over this block's 256 cols.
    // C/D layout: col = lane&15, row = (lane>>4)*4 + reg
    float* qbuf = (float*)&As[0][0];  // 4 KB, staging fully drained
    #pragma unroll
    for (int m = 0; m < 8; ++m) {
        #pragma unroll
        for (int r = 0; r < 4; ++r) {
            float s = 0.f;
            #pragma unroll
            for (int n = 0; n < 4; ++n) {
                float t = acc[m][n][r];
                s += t * t;
            }
            #pragma unroll
            for (int off = 1; off < 16; off <<= 1) s += __shfl_xor(s, off);
            if (r16 == 0) qbuf[wc * 256 + wr * 128 + m * 16 + g * 4 + r] = s;
        }
    }
    __syncthreads();
    if (tid < BM)
        qpart[(size_t)(brow + tid) * NB_N + nb] =
            qbuf[tid] + qbuf[256 + tid] + qbuf[512 + tid] + qbuf[768 + tid];
#undef STAGE
#undef TILE_BODY
}

// ---------------------------------------------------------------------------
// row_part: 32-block partial reduction of the per-row weighted ELBO terms.
// ---------------------------------------------------------------------------
__global__ __launch_bounds__(256) void row_part(const float* __restrict__ Y,
                                                const float* __restrict__ Cnt,
                                                const float* __restrict__ nld_p,
                                                const float* __restrict__ U,
                                                const float* __restrict__ qpart,
                                                double* __restrict__ dpart) {
    const int tid = threadIdx.x;
    const float nld = nld_p[0];
    const float inv_sig = expf(-nld);
    const float nprec = inv_sig * inv_sig;
    double s1 = 0.0, s2 = 0.0;
    const int base = blockIdx.x * 512;
    #pragma unroll
    for (int j = 0; j < 2; ++j) {
        int b = base + j * 256 + tid;
        float c = Cnt[b];
        const float4* qp = (const float4*)(qpart + (size_t)b * NB_N);
        float4 q0 = qp[0], q1 = qp[1];
        float q = q0.x + q0.y + q0.z + q0.w + q1.x + q1.y + q1.z + q1.w;
        float d = (Y[b] - U[b]) * inv_sig;
        float pl = -0.5f * d * d - nld - 0.5f * LOG2PI_F;
        float tt = 0.5f * q * c * c * nprec;
        s1 += (double)c;
        s2 += (double)((pl - tt) * c);
    }
    __shared__ double red[2][4];
    #pragma unroll
    for (int off = 32; off; off >>= 1) {
        s1 += __shfl_down(s1, off);
        s2 += __shfl_down(s2, off);
    }
    if ((tid & 63) == 0) { red[0][tid >> 6] = s1; red[1][tid >> 6] = s2; }
    __syncthreads();
    if (tid == 0) {
        dpart[blockIdx.x * 2 + 0] = red[0][0] + red[0][1] + red[0][2] + red[0][3];
        dpart[blockIdx.x * 2 + 1] = red[1][0] + red[1][1] + red[1][2] + red[1][3];
    }
}

// ---------------------------------------------------------------------------
// finalize2: combine partials + KL/wishart scalar terms. One block.
// ---------------------------------------------------------------------------
__global__ __launch_bounds__(256) void finalize2(const float* __restrict__ nld_p,
                                                 const float* __restrict__ Wm,
                                                 const float* __restrict__ Wld,
                                                 const double* __restrict__ dpart,
                                                 const float* __restrict__ misc_arr,
                                                 float* __restrict__ out) {
    const int tid = threadIdx.x;
    const float nld = nld_p[0];
    const float inv_sig = expf(-nld);
    const float nprec = inv_sig * inv_sig;

    double s1 = 0.0, s2 = 0.0;
    if (tid < 32) { s1 = dpart[tid * 2]; s2 = dpart[tid * 2 + 1]; }

    double wm2 = 0.0, tcd = 0.0, wls = 0.0, offs = 0.0;
    for (int i = tid; i < K_DIM; i += 256) {
        float w = Wm[i];
        wm2 += (double)w * (double)w;
        float ld = Wld[i];
        tcd += exp(2.0 * (double)ld);
        wls += (double)ld;
    }
    for (int i = tid; i < 1024; i += 256) offs += (double)misc_arr[i];

    __shared__ double red[6][4];
    double vals[6] = {s1, s2, wm2, tcd, wls, offs};
    #pragma unroll
    for (int s = 0; s < 6; ++s) {
        double v = vals[s];
        #pragma unroll
        for (int off = 32; off; off >>= 1) v += __shfl_down(v, off);
        if ((tid & 63) == 0) red[s][tid >> 6] = v;
    }
    __syncthreads();
    if (tid == 0) {
        double S1 = red[0][0] + red[0][1] + red[0][2] + red[0][3];
        double S2 = red[1][0] + red[1][1] + red[1][2] + red[1][3];
        double MSE = red[2][0] + red[2][1] + red[2][2] + red[2][3];
        double TCD = red[3][0] + red[3][1] + red[3][2] + red[3][3];
        double WLS = red[4][0] + red[4][1] + red[4][2] + red[4][3];
        double OFFS = red[5][0] + red[5][1] + red[5][2] + red[5][3];

        double trace_cov = OFFS + TCD;                   // sum(L*L)
        double kl = 0.5 * (MSE + trace_cov - 2.0 * WLS); // prior_scale=1
        double wish = 1.5 * (-2.0 * (double)nld) - 0.005 * (double)nprec;
        double elbo = S2 / S1 + 1e-4 * (wish - kl);
        out[0] = (float)(-elbo);
    }
}

// ---------------------------------------------------------------------------
extern "C" void kernel_launch(void* const* d_in, const int* in_sizes, int n_in,
                              void* d_out, int out_size, void* d_ws, size_t ws_size,
                              hipStream_t stream) {
    const float* x    = (const float*)d_in[0];
    const float* y    = (const float*)d_in[1];
    const float* cnt  = (const float*)d_in[2];
    // d_in[3] = noise_mean (unused by the reference math)
    const float* nld  = (const float*)d_in[4];
    const float* Wm   = (const float*)d_in[5];
    const float* Wld  = (const float*)d_in[6];
    const float* Woff = (const float*)d_in[7];

    char* ws = (char*)d_ws;
    bf16_t* Xb     = (bf16_t*)(ws);                 // 16384*2048*2 = 67108864
    bf16_t* Lt     = (bf16_t*)(ws + 67108864);      // 2048*2048*2  =  8388608
    float*  U      = (float*)(ws + 75497472);       // 16384*4      =    65536
    float*  qpart  = (float*)(ws + 75563008);       // 16384*8*4    =   524288
    double* dpart  = (double*)(ws + 76087296);      // 64*8         =      512
    float*  misc   = (float*)(ws + 76611584);       // 1024*4       =     4096

    build_Lt<<<dim3(32, 32), 256, 0, stream>>>(Woff, Wld, Lt, misc);
    prep_x<<<dim3(M_DIM), 256, 0, stream>>>(x, Wm, Xb, U);
    quad_gemm<<<dim3(NB_M, NB_N), 512, 0, stream>>>(Xb, Lt, qpart);
    row_part<<<dim3(32), 256, 0, stream>>>(y, cnt, nld, U, qpart, dpart);
    finalize2<<<1, 256, 0, stream>>>(nld, Wm, Wld, dpart, misc, (float*)d_out);
}

// Round 4
// 133.023 us; speedup vs baseline: 1.8066x; 1.8066x over previous
//
#include <hip/hip_runtime.h>
#include <hip/hip_bf16.h>
#include <math.h>

#define LOG2PI_F 1.8378770664093453f

typedef __bf16 bf16_t;
typedef bf16_t bf16x8 __attribute__((ext_vector_type(8)));
typedef bf16_t bf16x4 __attribute__((ext_vector_type(4)));
typedef float f32x4 __attribute__((ext_vector_type(4)));

#define M_DIM 16384
#define K_DIM 2048
#define N_DIM 2048
#define BM 256
#define BN 128
#define BK 64
#define NB_N (N_DIM / BN) /* 16 */
#define NB_M (M_DIM / BM) /* 64 */

// async global->LDS, 16B per lane. LDS dest is wave-uniform base + lane*16.
__device__ __forceinline__ void gload16(const void* g, void* l) {
    __builtin_amdgcn_global_load_lds(
        (__attribute__((address_space(1))) void*)g,
        (__attribute__((address_space(3))) void*)l, 16, 0, 0);
}

// ---------------------------------------------------------------------------
// Build Lt[j][i] = L[i][j] in bf16 + partial sums of strict-lower Woff^2.
// ---------------------------------------------------------------------------
__global__ __launch_bounds__(256) void build_Lt(const float* __restrict__ Woff,
                                                const float* __restrict__ Wld,
                                                bf16_t* __restrict__ Lt,
                                                float* __restrict__ misc_arr) {
    __shared__ float tile[64][65];
    __shared__ float red[4];
    const int jt = blockIdx.x * 64;
    const int it = blockIdx.y * 64;
    const int tid = threadIdx.x;
    float ss = 0.f;

    if (it + 63 >= jt) {
        for (int e = tid; e < 4096; e += 256) {
            int r = e >> 6, c = e & 63;
            tile[r][c] = Woff[(size_t)(it + r) * K_DIM + (jt + c)];
        }
    }
    __syncthreads();

    for (int e = tid; e < 4096; e += 256) {
        int jr = e >> 6, ic = e & 63;
        int i = it + ic, j = jt + jr;
        float v = 0.f;
        if (i > j) {
            v = tile[ic][jr];
            ss += v * v;
        } else if (i == j) {
            v = expf(Wld[i]);
        }
        Lt[(size_t)j * K_DIM + i] = (bf16_t)v;
    }

    #pragma unroll
    for (int off = 32; off; off >>= 1) ss += __shfl_down(ss, off);
    if ((tid & 63) == 0) red[tid >> 6] = ss;
    __syncthreads();
    if (tid == 0)
        misc_arr[blockIdx.y * 32 + blockIdx.x] = red[0] + red[1] + red[2] + red[3];
}

// ---------------------------------------------------------------------------
// Cast x -> bf16 and fuse pred_mean GEMV u[b] = dot(x[b], W_mean).
// ---------------------------------------------------------------------------
__global__ __launch_bounds__(256) void prep_x(const float* __restrict__ X,
                                              const float* __restrict__ Wm,
                                              bf16_t* __restrict__ Xb,
                                              float* __restrict__ U) {
    const int b = blockIdx.x;
    const int tid = threadIdx.x;
    const float* xr = X + (size_t)b * K_DIM;
    bf16_t* xo = Xb + (size_t)b * K_DIM;
    __shared__ float red[4];
    float dot = 0.f;
    #pragma unroll
    for (int h = 0; h < 2; ++h) {
        int base = h * 1024 + tid * 4;
        float4 v = *(const float4*)(xr + base);
        float4 w = *(const float4*)(Wm + base);
        dot += v.x * w.x + v.y * w.y + v.z * w.z + v.w * w.w;
        bf16x4 p = {(bf16_t)v.x, (bf16_t)v.y, (bf16_t)v.z, (bf16_t)v.w};
        *(bf16x4*)(xo + base) = p;
    }
    #pragma unroll
    for (int off = 32; off; off >>= 1) dot += __shfl_down(dot, off);
    if ((tid & 63) == 0) red[tid >> 6] = dot;
    __syncthreads();
    if (tid == 0) U[b] = red[0] + red[1] + red[2] + red[3];
}

// ---------------------------------------------------------------------------
// quad_gemm 256x128, BK=64, 3-deep LDS pipeline, counted vmcnt(6).
// 8 waves as 4M x 2N; per wave 64x64 output = acc[4][4] (64 AGPR).
// Tile i: compute buf[i%3]; stage tile i+2 into buf[(i+2)%3] (6 loads:
// A=4, B=2 per thread, spread 3+3 over the 2 phases). End-of-tile wait
// vmcnt(6) retires tile i+1's loads while i+2's 6 stay in flight.
// ---------------------------------------------------------------------------
__device__ __forceinline__ bf16x8 ldsfrag(const bf16_t* base, int row, int ks, int g) {
    int byteoff = ((row * BK + ks * 32 + g * 8) * 2) ^ ((row & 7) << 4);
    return *(const bf16x8*)((const char*)base + byteoff);
}

__global__ __launch_bounds__(512, 2) void quad_gemm(const bf16_t* __restrict__ Xb,
                                                    const bf16_t* __restrict__ Lt,
                                                    float* __restrict__ qpart) {
    __shared__ bf16_t As[3][BM * BK];   // 3 x 32 KB
    __shared__ bf16_t Bs[3][BN * BK];   // 3 x 16 KB  (total 144 KB)

    const int mb = blockIdx.x, nb = blockIdx.y;  // nb ascending => NT descending
    const int tid = threadIdx.x;
    const int lane = tid & 63;
    const int wid = tid >> 6;               // 0..7
    const int wr = wid >> 1, wc = wid & 1;  // 4M x 2N wave grid
    const int g = lane >> 4, r16 = lane & 15;
    const int brow = mb * BM, bcol = nb * BN;
    const int NT = (K_DIM - bcol) >> 6;     // 32 - 2*nb, in [2,32]

    // staging sources (per-lane, source-swizzled chunk; involution w/ read XOR)
    const int srow = lane >> 3;
    const int scol = (lane & 7) ^ srow;
    const bf16_t* pA[4];
    const bf16_t* pB[2];
    #pragma unroll
    for (int j = 0; j < 4; ++j)
        pA[j] = Xb + (size_t)(brow + wid * 32 + j * 8 + srow) * K_DIM + bcol + scol * 8;
    #pragma unroll
    for (int j = 0; j < 2; ++j)
        pB[j] = Lt + (size_t)(bcol + wid * 16 + j * 8 + srow) * K_DIM + bcol + scol * 8;

#define STAGE_TILE(ST)                                                      \
    { _Pragma("unroll") for (int j = 0; j < 4; ++j)                         \
          gload16(pA[j], (char*)As[ST] + (wid * 4 + j) * 1024);             \
      _Pragma("unroll") for (int j = 0; j < 2; ++j)                         \
          gload16(pB[j], (char*)Bs[ST] + (wid * 2 + j) * 1024);             \
      _Pragma("unroll") for (int j = 0; j < 4; ++j) pA[j] += BK;            \
      _Pragma("unroll") for (int j = 0; j < 2; ++j) pB[j] += BK; }

    f32x4 acc[4][4];
    const f32x4 zero = {0.f, 0.f, 0.f, 0.f};
    #pragma unroll
    for (int m = 0; m < 4; ++m)
        #pragma unroll
        for (int n = 0; n < 4; ++n) acc[m][n] = zero;

    // prologue: tiles 0,1 -> bufs 0,1; wait tile0 (tile1's 6 stay in flight)
    STAGE_TILE(0)
    STAGE_TILE(1)
    asm volatile("s_waitcnt vmcnt(6)" ::: "memory");
    asm volatile("s_barrier" ::: "memory");

    int cur = 0, st = 2;
    for (int i = 0; i < NT; ++i) {
        const bf16_t* Ab = As[cur];
        const bf16_t* Bb = Bs[cur];
        char* sA = (char*)As[st];
        char* sB = (char*)Bs[st];
        const bool stg = (i + 2 < NT);

        // ---- phase 0 (ks = 0): 8 ds_read_b128 + 3 staging loads + 16 MFMA
        {
            bf16x8 a[4], b[4];
            #pragma unroll
            for (int m = 0; m < 4; ++m)
                a[m] = ldsfrag(Ab, wr * 64 + m * 16 + r16, 0, g);
            #pragma unroll
            for (int n = 0; n < 4; ++n)
                b[n] = ldsfrag(Bb, wc * 64 + n * 16 + r16, 0, g);
            if (stg) {
                gload16(pA[0], sA + (wid * 4 + 0) * 1024);
                gload16(pA[1], sA + (wid * 4 + 1) * 1024);
                gload16(pA[2], sA + (wid * 4 + 2) * 1024);
            }
            asm volatile("s_waitcnt lgkmcnt(0)" ::: "memory");
            __builtin_amdgcn_sched_barrier(0);
            __builtin_amdgcn_s_setprio(1);
            #pragma unroll
            for (int m = 0; m < 4; ++m)
                #pragma unroll
                for (int n = 0; n < 4; ++n)
                    acc[m][n] = __builtin_amdgcn_mfma_f32_16x16x32_bf16(
                        a[m], b[n], acc[m][n], 0, 0, 0);
            __builtin_amdgcn_s_setprio(0);
        }
        asm volatile("s_barrier" ::: "memory");

        // ---- phase 1 (ks = 1): 8 ds_read_b128 + 3 staging loads + 16 MFMA
        {
            bf16x8 a[4], b[4];
            #pragma unroll
            for (int m = 0; m < 4; ++m)
                a[m] = ldsfrag(Ab, wr * 64 + m * 16 + r16, 1, g);
            #pragma unroll
            for (int n = 0; n < 4; ++n)
                b[n] = ldsfrag(Bb, wc * 64 + n * 16 + r16, 1, g);
            if (stg) {
                gload16(pA[3], sA + (wid * 4 + 3) * 1024);
                gload16(pB[0], sB + (wid * 2 + 0) * 1024);
                gload16(pB[1], sB + (wid * 2 + 1) * 1024);
                #pragma unroll
                for (int j = 0; j < 4; ++j) pA[j] += BK;
                #pragma unroll
                for (int j = 0; j < 2; ++j) pB[j] += BK;
            }
            asm volatile("s_waitcnt lgkmcnt(0)" ::: "memory");
            __builtin_amdgcn_sched_barrier(0);
            __builtin_amdgcn_s_setprio(1);
            #pragma unroll
            for (int m = 0; m < 4; ++m)
                #pragma unroll
                for (int n = 0; n < 4; ++n)
                    acc[m][n] = __builtin_amdgcn_mfma_f32_16x16x32_bf16(
                        a[m], b[n], acc[m][n], 0, 0, 0);
            __builtin_amdgcn_s_setprio(0);
        }
        if (stg)
            asm volatile("s_waitcnt vmcnt(6)" ::: "memory");  // tile i+1 landed
        else if (i + 1 < NT)
            asm volatile("s_waitcnt vmcnt(0)" ::: "memory");  // tail drain
        asm volatile("s_barrier" ::: "memory");
        cur = (cur == 2) ? 0 : cur + 1;
        st = (st == 2) ? 0 : st + 1;
    }

    // epilogue: per-row sum of squares over this block's 128 cols.
    // C/D layout: col = lane&15, row = (lane>>4)*4 + reg
    float* qbuf = (float*)&As[0][0];  // 2 KB; all staging drained
    #pragma unroll
    for (int m = 0; m < 4; ++m) {
        #pragma unroll
        for (int r = 0; r < 4; ++r) {
            float s = 0.f;
            #pragma unroll
            for (int n = 0; n < 4; ++n) {
                float t = acc[m][n][r];
                s += t * t;
            }
            #pragma unroll
            for (int off = 1; off < 16; off <<= 1) s += __shfl_xor(s, off);
            if (r16 == 0) qbuf[wc * 256 + wr * 64 + m * 16 + g * 4 + r] = s;
        }
    }
    __syncthreads();
    if (tid < BM)
        qpart[(size_t)(brow + tid) * NB_N + nb] = qbuf[tid] + qbuf[256 + tid];
#undef STAGE_TILE
}

// ---------------------------------------------------------------------------
// row_part: 32-block partial reduction of the per-row weighted ELBO terms.
// ---------------------------------------------------------------------------
__global__ __launch_bounds__(256) void row_part(const float* __restrict__ Y,
                                                const float* __restrict__ Cnt,
                                                const float* __restrict__ nld_p,
                                                const float* __restrict__ U,
                                                const float* __restrict__ qpart,
                                                double* __restrict__ dpart) {
    const int tid = threadIdx.x;
    const float nld = nld_p[0];
    const float inv_sig = expf(-nld);
    const float nprec = inv_sig * inv_sig;
    double s1 = 0.0, s2 = 0.0;
    const int base = blockIdx.x * 512;
    #pragma unroll
    for (int j = 0; j < 2; ++j) {
        int b = base + j * 256 + tid;
        float c = Cnt[b];
        const float4* qp = (const float4*)(qpart + (size_t)b * NB_N);
        float q = 0.f;
        #pragma unroll
        for (int v4 = 0; v4 < 4; ++v4) {
            float4 qv = qp[v4];
            q += qv.x + qv.y + qv.z + qv.w;
        }
        float d = (Y[b] - U[b]) * inv_sig;
        float pl = -0.5f * d * d - nld - 0.5f * LOG2PI_F;
        float tt = 0.5f * q * c * c * nprec;
        s1 += (double)c;
        s2 += (double)((pl - tt) * c);
    }
    __shared__ double red[2][4];
    #pragma unroll
    for (int off = 32; off; off >>= 1) {
        s1 += __shfl_down(s1, off);
        s2 += __shfl_down(s2, off);
    }
    if ((tid & 63) == 0) { red[0][tid >> 6] = s1; red[1][tid >> 6] = s2; }
    __syncthreads();
    if (tid == 0) {
        dpart[blockIdx.x * 2 + 0] = red[0][0] + red[0][1] + red[0][2] + red[0][3];
        dpart[blockIdx.x * 2 + 1] = red[1][0] + red[1][1] + red[1][2] + red[1][3];
    }
}

// ---------------------------------------------------------------------------
// finalize2: combine partials + KL/wishart scalar terms. One block.
// ---------------------------------------------------------------------------
__global__ __launch_bounds__(256) void finalize2(const float* __restrict__ nld_p,
                                                 const float* __restrict__ Wm,
                                                 const float* __restrict__ Wld,
                                                 const double* __restrict__ dpart,
                                                 const float* __restrict__ misc_arr,
                                                 float* __restrict__ out) {
    const int tid = threadIdx.x;
    const float nld = nld_p[0];
    const float inv_sig = expf(-nld);
    const float nprec = inv_sig * inv_sig;

    double s1 = 0.0, s2 = 0.0;
    if (tid < 32) { s1 = dpart[tid * 2]; s2 = dpart[tid * 2 + 1]; }

    double wm2 = 0.0, tcd = 0.0, wls = 0.0, offs = 0.0;
    for (int i = tid; i < K_DIM; i += 256) {
        float w = Wm[i];
        wm2 += (double)w * (double)w;
        float ld = Wld[i];
        tcd += exp(2.0 * (double)ld);
        wls += (double)ld;
    }
    for (int i = tid; i < 1024; i += 256) offs += (double)misc_arr[i];

    __shared__ double red[6][4];
    double vals[6] = {s1, s2, wm2, tcd, wls, offs};
    #pragma unroll
    for (int s = 0; s < 6; ++s) {
        double v = vals[s];
        #pragma unroll
        for (int off = 32; off; off >>= 1) v += __shfl_down(v, off);
        if ((tid & 63) == 0) red[s][tid >> 6] = v;
    }
    __syncthreads();
    if (tid == 0) {
        double S1 = red[0][0] + red[0][1] + red[0][2] + red[0][3];
        double S2 = red[1][0] + red[1][1] + red[1][2] + red[1][3];
        double MSE = red[2][0] + red[2][1] + red[2][2] + red[2][3];
        double TCD = red[3][0] + red[3][1] + red[3][2] + red[3][3];
        double WLS = red[4][0] + red[4][1] + red[4][2] + red[4][3];
        double OFFS = red[5][0] + red[5][1] + red[5][2] + red[5][3];

        double trace_cov = OFFS + TCD;                   // sum(L*L)
        double kl = 0.5 * (MSE + trace_cov - 2.0 * WLS); // prior_scale=1
        double wish = 1.5 * (-2.0 * (double)nld) - 0.005 * (double)nprec;
        double elbo = S2 / S1 + 1e-4 * (wish - kl);
        out[0] = (float)(-elbo);
    }
}

// ---------------------------------------------------------------------------
extern "C" void kernel_launch(void* const* d_in, const int* in_sizes, int n_in,
                              void* d_out, int out_size, void* d_ws, size_t ws_size,
                              hipStream_t stream) {
    const float* x    = (const float*)d_in[0];
    const float* y    = (const float*)d_in[1];
    const float* cnt  = (const float*)d_in[2];
    // d_in[3] = noise_mean (unused by the reference math)
    const float* nld  = (const float*)d_in[4];
    const float* Wm   = (const float*)d_in[5];
    const float* Wld  = (const float*)d_in[6];
    const float* Woff = (const float*)d_in[7];

    char* ws = (char*)d_ws;
    bf16_t* Xb     = (bf16_t*)(ws);                 // [0, 67108864)
    bf16_t* Lt     = (bf16_t*)(ws + 67108864);      // [67108864, 75497472)
    float*  U      = (float*)(ws + 75497472);       // 16384*4
    float*  qpart  = (float*)(ws + 75563008);       // 16384*16*4 = 1 MB
    float*  misc   = (float*)(ws + 76611584);       // 1024*4
    // dpart (512 B) aliases Lt's base: Lt is consumed only by quad_gemm,
    // which completes before row_part writes here; build_Lt rewrites Lt
    // at the start of every launch, so replays stay deterministic.
    double* dpart  = (double*)(ws + 67108864);

    build_Lt<<<dim3(32, 32), 256, 0, stream>>>(Woff, Wld, Lt, misc);
    prep_x<<<dim3(M_DIM), 256, 0, stream>>>(x, Wm, Xb, U);
    quad_gemm<<<dim3(NB_M, NB_N), 512, 0, stream>>>(Xb, Lt, qpart);
    row_part<<<dim3(32), 256, 0, stream>>>(y, cnt, nld, U, qpart, dpart);
    finalize2<<<1, 256, 0, stream>>>(nld, Wm, Wld, dpart, misc, (float*)d_out);
}